// Round 2
// baseline (306.249 us; speedup 1.0000x reference)
//
#include <hip/hip_runtime.h>
#include <stdint.h>

typedef __attribute__((ext_vector_type(8))) short short8;
typedef __attribute__((ext_vector_type(4))) float floatx4;

// ---------- helpers ----------
__device__ __forceinline__ float bf16_to_f(uint16_t u) {
    union { uint32_t i; float f; } v; v.i = ((uint32_t)u) << 16; return v.f;
}
__device__ __forceinline__ uint16_t f_to_bf16(float f) {
    union { uint32_t i; float f; } v; v.f = f;
    uint32_t u = v.i;
    u += 0x7FFFu + ((u >> 16) & 1u);   // round-to-nearest-even
    return (uint16_t)(u >> 16);
}
__device__ __forceinline__ void gload16(const void* g, void* l) {
    __builtin_amdgcn_global_load_lds(
        (const __attribute__((address_space(1))) void*)g,
        (__attribute__((address_space(3))) void*)l, 16, 0, 0);
}
__device__ __forceinline__ float rcpf(float x) { return __builtin_amdgcn_rcpf(x); }

// LDS-only barrier: waits LDS ops, does NOT drain vmcnt.
__device__ __forceinline__ void bar_lds() {
    asm volatile("s_waitcnt lgkmcnt(0)" ::: "memory");
    __builtin_amdgcn_s_barrier();
    asm volatile("" ::: "memory");
}

#define B_  32
#define T_  512
#define CF_ 2048
#define H_  128
#define G4_ 512   // 4*H
#define LOG2E 1.4426950408889634f

// =====================================================================
// k_cvt_all: all 6 weight tensors fp32 -> bf16 in ONE launch.
// =====================================================================
__global__ __launch_bounds__(256) void k_cvt_all(
        const float* __restrict__ Wfc, const float* __restrict__ Wih_f,
        const float* __restrict__ Wih_b, const float* __restrict__ Whh_f,
        const float* __restrict__ Whh_b, const float* __restrict__ Wout,
        uint16_t* __restrict__ WfcB, uint16_t* __restrict__ WihB,
        uint16_t* __restrict__ WhhB, uint16_t* __restrict__ WoutB) {
    const int blk = blockIdx.x;
    const float* s; uint16_t* d; int off;
    if (blk < 256)      { s = Wfc;   d = WfcB;          off = blk; }
    else if (blk < 320) { s = Wih_f; d = WihB;          off = blk - 256; }
    else if (blk < 384) { s = Wih_b; d = WihB + 65536;  off = blk - 320; }
    else if (blk < 448) { s = Whh_f; d = WhhB;          off = blk - 384; }
    else if (blk < 512) { s = Whh_b; d = WhhB + 65536;  off = blk - 448; }
    else                { s = Wout;  d = WoutB;         off = blk - 512; }
    const int i = off * 1024 + threadIdx.x * 4;
    float4 v = *(const float4*)&s[i];
    ushort4 o;
    o.x = f_to_bf16(v.x); o.y = f_to_bf16(v.y);
    o.z = f_to_bf16(v.z); o.w = f_to_bf16(v.w);
    *(ushort4*)&d[i] = o;
}

// =====================================================================
// k_fc1x: fused  x-transpose + fc1 + input-projection.
// RESTRUCTURED: 256 thr / 4 waves, t-tile 32, grid (16,32)=512 blocks
// -> 2 WG/CU so an independent workgroup fills barrier/latency holes.
// Per-wave work unchanged. vmcnt fence moved BEFORE barrier B so all
// waves' As gloads are visible after the barrier (cross-wave correct).
// =====================================================================
__global__ __launch_bounds__(256, 2) void k_fc1x(const float* __restrict__ x,
                                              const uint16_t* __restrict__ WfcB,
                                              const float* __restrict__ bfc,
                                              const uint16_t* __restrict__ WihB,
                                              const float* __restrict__ b_f,
                                              const float* __restrict__ b_b,
                                              uint16_t* __restrict__ Xp) {
    __shared__ float tile[32 * 65];                    // [t][cf] fp32 (32t x 64cf)
    __shared__ __align__(16) uint16_t As[8192];        // W chunk-major (8c x 128d x 8)
    __shared__ __align__(16) uint16_t Bs[2176];        // xT chunk-major (8c x 34t x 8)
    __shared__ __align__(16) uint16_t Hs2[4352];       // Hfc chunk-major (16c x 34t x 8)

    const int bb = blockIdx.y, n0 = blockIdx.x * 32;
    const int tid = threadIdx.x, w = tid >> 6, l = tid & 63;
    const int lm = l & 15, lk = l >> 4;
    const float* xb = x + (size_t)bb * CF_ * T_;

    // stage-1 mapping (x load / tile write): 8 lanes cover 32 t, 32 cf rows (+32)
    const int t4 = (tid & 7) * 4, cf_r = tid >> 3;     // cf_r in 0..31
    // stage-2 mapping (tile read / Bs write): 16 lanes cover 64 k, 16 t rows (+16)
    const int kk = (tid & 15) * 4, t_r = tid >> 4;     // t_r in 0..15

    float4 xv0, xv1;
    {
        const float* p = &xb[(size_t)cf_r * T_ + n0 + t4];
        xv0 = *(const float4*)p;
        xv1 = *(const float4*)(p + 32 * T_);
    }

    // ---------------- Phase A ----------------
    // 4 waves tile the 128d x 32t output as 4 (d) x 1 (t) of 32x32.
    const int wmA = w * 32;
    floatx4 acc[2][2] = {};
    for (int i = 0; i < 32; ++i) {
        const int k0 = i * 64;
        // stage1: fp32 transpose tile (xv loaded during previous iteration)
        tile[(t4 + 0) * 65 + cf_r] = xv0.x;
        tile[(t4 + 1) * 65 + cf_r] = xv0.y;
        tile[(t4 + 2) * 65 + cf_r] = xv0.z;
        tile[(t4 + 3) * 65 + cf_r] = xv0.w;
        tile[(t4 + 0) * 65 + cf_r + 32] = xv1.x;
        tile[(t4 + 1) * 65 + cf_r + 32] = xv1.y;
        tile[(t4 + 2) * 65 + cf_r + 32] = xv1.z;
        tile[(t4 + 3) * 65 + cf_r + 32] = xv1.w;
        bar_lds();   // barrier A: tile visible; all waves' prev frag reads done
        // A staging: wave w stages chunks w and w+4, rows l and 64+l each
        gload16(WfcB + (size_t)l * CF_ + k0 + w * 8,              As + (w * 128 + l) * 8);
        gload16(WfcB + (size_t)(64 + l) * CF_ + k0 + w * 8,       As + (w * 128 + 64 + l) * 8);
        gload16(WfcB + (size_t)l * CF_ + k0 + (w + 4) * 8,        As + ((w + 4) * 128 + l) * 8);
        gload16(WfcB + (size_t)(64 + l) * CF_ + k0 + (w + 4) * 8, As + ((w + 4) * 128 + 64 + l) * 8);
        asm volatile("" ::: "memory");   // pin vmcnt FIFO order: gloads before x prefetch
        // prefetch next x block (stays in flight across the fence+barrier)
        if (i < 31) {
            const float* p = &xb[(size_t)(k0 + 64 + cf_r) * T_ + n0 + t4];
            xv0 = *(const float4*)p;
            xv1 = *(const float4*)(p + 32 * T_);
        }
        // stage2: tile -> bf16 chunk-major Bs
        #pragma unroll
        for (int pass = 0; pass < 2; ++pass) {
            const int tr = t_r + pass * 16;
            ushort4 o;
            o.x = f_to_bf16(tile[tr * 65 + kk + 0]);
            o.y = f_to_bf16(tile[tr * 65 + kk + 1]);
            o.z = f_to_bf16(tile[tr * 65 + kk + 2]);
            o.w = f_to_bf16(tile[tr * 65 + kk + 3]);
            *(ushort4*)&Bs[((kk >> 3) * 34 + tr) * 8 + (kk & 7)] = o;
        }
        // own As-gloads retired BEFORE barrier -> after barrier ALL waves'
        // staging is visible. The 2 newest (x prefetch) keep flying.
        if (i < 31) asm volatile("s_waitcnt vmcnt(2)" ::: "memory");
        else        asm volatile("s_waitcnt vmcnt(0)" ::: "memory");
        bar_lds();   // barrier B: Bs + As visible
        __builtin_amdgcn_sched_barrier(0);
        // frags + MFMA
        short8 a[2][2], bfr[2][2];
        #pragma unroll
        for (int kf = 0; kf < 2; ++kf) {
            #pragma unroll
            for (int mf = 0; mf < 2; ++mf)
                a[mf][kf] = *(const short8*)&As[((kf * 4 + lk) * 128 + wmA + mf * 16 + lm) * 8];
            #pragma unroll
            for (int nf = 0; nf < 2; ++nf)
                bfr[nf][kf] = *(const short8*)&Bs[((kf * 4 + lk) * 34 + nf * 16 + lm) * 8];
        }
        #pragma unroll
        for (int mf = 0; mf < 2; ++mf)
            #pragma unroll
            for (int nf = 0; nf < 2; ++nf) {
                acc[mf][nf] = __builtin_amdgcn_mfma_f32_16x16x32_bf16(a[mf][0], bfr[nf][0], acc[mf][nf], 0, 0, 0);
                acc[mf][nf] = __builtin_amdgcn_mfma_f32_16x16x32_bf16(a[mf][1], bfr[nf][1], acc[mf][nf], 0, 0, 0);
            }
    }
    bar_lds();
    // epilogue A: bias + bf16 -> Hs2 chunk-major (stride 34)
    #pragma unroll
    for (int mf = 0; mf < 2; ++mf) {
        const int d0 = wmA + mf * 16 + lk * 4;
        const float4 bv = *(const float4*)&bfc[d0];
        const int c = ((wmA + mf * 16) >> 3) + (lk >> 1);
        #pragma unroll
        for (int nf = 0; nf < 2; ++nf) {
            const int t = nf * 16 + lm;
            ushort4 o;
            o.x = f_to_bf16(acc[mf][nf][0] + bv.x);
            o.y = f_to_bf16(acc[mf][nf][1] + bv.y);
            o.z = f_to_bf16(acc[mf][nf][2] + bv.z);
            o.w = f_to_bf16(acc[mf][nf][3] + bv.w);
            *(ushort4*)&Hs2[(c * 34 + t) * 8 + (lk & 1) * 4] = o;
        }
    }
    bar_lds();

    // ---------------- Phase B ----------------
    // 4 waves: dir = w>>1, g-half = (w&1)*256; 4 iterations of 64 g each.
    const int dirw = w >> 1;
    const int db   = dirw * B_ + bb;
    const uint16_t* Wp = WihB + (size_t)dirw * (G4_ * H_);
    const float* bi = dirw ? b_b : b_f;
    #pragma unroll
    for (int it = 0; it < 4; ++it) {
        const int gbase = (w & 1) * 256 + it * 64;
        short8 aw[4][4];
        #pragma unroll
        for (int mf = 0; mf < 4; ++mf)
            #pragma unroll
            for (int kf = 0; kf < 4; ++kf)
                aw[mf][kf] = *(const short8*)&Wp[(size_t)(gbase + mf * 16 + lm) * H_ + kf * 32 + lk * 8];
        floatx4 acc2[4][2] = {};
        #pragma unroll
        for (int nf = 0; nf < 2; ++nf) {
            short8 bbf[4];
            #pragma unroll
            for (int kf = 0; kf < 4; ++kf)
                bbf[kf] = *(const short8*)&Hs2[((kf * 4 + lk) * 34 + nf * 16 + lm) * 8];
            #pragma unroll
            for (int mf = 0; mf < 4; ++mf)
                #pragma unroll
                for (int kf = 0; kf < 4; ++kf)
                    acc2[mf][nf] = __builtin_amdgcn_mfma_f32_16x16x32_bf16(aw[mf][kf], bbf[kf], acc2[mf][nf], 0, 0, 0);
        }
        #pragma unroll
        for (int mf = 0; mf < 4; ++mf) {
            const int g0 = gbase + mf * 16 + lk * 4;
            const float4 bv = *(const float4*)&bi[g0];
            #pragma unroll
            for (int nf = 0; nf < 2; ++nf) {
                const int t = n0 + nf * 16 + lm;
                ushort4 o;
                o.x = f_to_bf16(acc2[mf][nf][0] + bv.x);
                o.y = f_to_bf16(acc2[mf][nf][1] + bv.y);
                o.z = f_to_bf16(acc2[mf][nf][2] + bv.z);
                o.w = f_to_bf16(acc2[mf][nf][3] + bv.w);
                *(ushort4*)&Xp[((size_t)db * T_ + t) * G4_ + g0] = o;
            }
        }
    }
}

// =====================================================================
// k_lstm: MFMA recurrence, LDS-only barriers (hs stores fire-and-forget).
// =====================================================================
__global__ __launch_bounds__(512) void k_lstm(const uint16_t* __restrict__ Xp,
                                              const uint16_t* __restrict__ WhhB,
                                              uint16_t* __restrict__ hs) {
    __shared__ __align__(16) uint16_t h_sh[16 * 136];
    __shared__ float z_sh[16 * 516];
    const int dir = blockIdx.y, t0 = blockIdx.x * 16;
    const int tid = threadIdx.x, w = tid >> 6, l = tid & 63;
    const int lm = l & 15, lk = l >> 4;
    const int gw = w * 64;
    const uint16_t* Wp = WhhB + dir * (G4_ * H_);

    short8 bw[4][4];
    #pragma unroll
    for (int nf = 0; nf < 4; ++nf)
        #pragma unroll
        for (int kf = 0; kf < 4; ++kf)
            bw[nf][kf] = *(const short8*)&Wp[(size_t)(gw + nf * 16 + lm) * H_ + kf * 32 + lk * 8];

    for (int i = tid; i < 16 * 136; i += 512) h_sh[i] = 0;
    const int hh = tid & 127, tq = tid >> 7;
    float c[4] = {0.f, 0.f, 0.f, 0.f};
    bar_lds();

    for (int s = 0; s < 32; ++s) {
        const int b_idx = dir ? (31 - s) : s;
        const uint16_t* xp = Xp + ((size_t)(dir * B_ + b_idx) * T_ + t0) * G4_;
        uint16_t xv[4][4];
        #pragma unroll
        for (int j = 0; j < 4; ++j)
            #pragma unroll
            for (int gg = 0; gg < 4; ++gg)
                xv[j][gg] = xp[(size_t)(tq * 4 + j) * G4_ + gg * H_ + hh];

        short8 af[4];
        #pragma unroll
        for (int kf = 0; kf < 4; ++kf)
            af[kf] = *(const short8*)&h_sh[lm * 136 + kf * 32 + lk * 8];
        floatx4 acc[4] = {};
        #pragma unroll
        for (int nf = 0; nf < 4; ++nf)
            #pragma unroll
            for (int kf = 0; kf < 4; ++kf)
                acc[nf] = __builtin_amdgcn_mfma_f32_16x16x32_bf16(af[kf], bw[nf][kf], acc[nf], 0, 0, 0);
        #pragma unroll
        for (int nf = 0; nf < 4; ++nf)
            #pragma unroll
            for (int r = 0; r < 4; ++r)
                z_sh[(lk * 4 + r) * 516 + gw + nf * 16 + lm] = acc[nf][r];
        bar_lds();

        #pragma unroll
        for (int j = 0; j < 4; ++j) {
            const int t = tq * 4 + j;
            const float* zr = &z_sh[t * 516];
            float zi = zr[hh]            + bf16_to_f(xv[j][0]);
            float zf = zr[H_ + hh]       + bf16_to_f(xv[j][1]);
            float zg = zr[2 * H_ + hh]   + bf16_to_f(xv[j][2]);
            float zo = zr[3 * H_ + hh]   + bf16_to_f(xv[j][3]);
            float si = rcpf(1.f + __builtin_amdgcn_exp2f(-LOG2E * zi));
            float sf = rcpf(1.f + __builtin_amdgcn_exp2f(-LOG2E * zf));
            float so = rcpf(1.f + __builtin_amdgcn_exp2f(-LOG2E * zo));
            float tg = 1.f - 2.f * rcpf(1.f + __builtin_amdgcn_exp2f(2.f * LOG2E * zg));
            c[j] = sf * c[j] + si * tg;
            float tc = 1.f - 2.f * rcpf(1.f + __builtin_amdgcn_exp2f(2.f * LOG2E * c[j]));
            float hn = so * tc;
            uint16_t hb = f_to_bf16(hn);
            h_sh[t * 136 + hh] = hb;
            hs[((size_t)b_idx * T_ + t0 + t) * 256 + dir * H_ + hh] = hb;
        }
        bar_lds();
    }
}

// =====================================================================
// k_outm: out[b][e][t] fp32 = W_out(128x256) @ hs[b]^T + b_out
// 64x64 tiles, BK=64, grid (8, 2, 32)
// =====================================================================
__global__ __launch_bounds__(256) void k_outm(const uint16_t* __restrict__ WoutB,
                                              const uint16_t* __restrict__ hs,
                                              const float* __restrict__ bout,
                                              float* __restrict__ out) {
    __shared__ __align__(16) uint16_t As[4096], Bs[4096];
    const int b = blockIdx.z, m0 = blockIdx.y * 64, n0 = blockIdx.x * 64;
    const int tid = threadIdx.x, w = tid >> 6, l = tid & 63;
    const int wm = (w >> 1) * 32, wn = (w & 1) * 32;
    const int lm = l & 15, lk = l >> 4;
    const uint16_t* A = WoutB + (size_t)m0 * 256;
    const uint16_t* Bp = hs + ((size_t)b * T_ + n0) * 256;
    floatx4 acc[2][2] = {};
    const uint16_t* gA = A + (size_t)l * 256;
    const uint16_t* gB = Bp + (size_t)l * 256;
    for (int k0 = 0; k0 < 256; k0 += 64) {
        __syncthreads();
        gload16(gA + k0 + (2 * w) * 8,     As + ((2 * w) * 64 + l) * 8);
        gload16(gA + k0 + (2 * w + 1) * 8, As + ((2 * w + 1) * 64 + l) * 8);
        gload16(gB + k0 + (2 * w) * 8,     Bs + ((2 * w) * 64 + l) * 8);
        gload16(gB + k0 + (2 * w + 1) * 8, Bs + ((2 * w + 1) * 64 + l) * 8);
        __syncthreads();
        short8 a[2][2], bfr[2][2];
        #pragma unroll
        for (int kf = 0; kf < 2; ++kf) {
            #pragma unroll
            for (int mf = 0; mf < 2; ++mf)
                a[mf][kf] = *(const short8*)&As[((kf * 4 + lk) * 64 + wm + mf * 16 + lm) * 8];
            #pragma unroll
            for (int nf = 0; nf < 2; ++nf)
                bfr[nf][kf] = *(const short8*)&Bs[((kf * 4 + lk) * 64 + wn + nf * 16 + lm) * 8];
        }
        #pragma unroll
        for (int mf = 0; mf < 2; ++mf)
            #pragma unroll
            for (int nf = 0; nf < 2; ++nf) {
                acc[mf][nf] = __builtin_amdgcn_mfma_f32_16x16x32_bf16(a[mf][0], bfr[nf][0], acc[mf][nf], 0, 0, 0);
                acc[mf][nf] = __builtin_amdgcn_mfma_f32_16x16x32_bf16(a[mf][1], bfr[nf][1], acc[mf][nf], 0, 0, 0);
            }
    }
    #pragma unroll
    for (int mf = 0; mf < 2; ++mf) {
        const int e0 = m0 + wm + mf * 16 + lk * 4;
        const float4 bv = *(const float4*)&bout[e0];
        #pragma unroll
        for (int nf = 0; nf < 2; ++nf) {
            const int t = n0 + wn + nf * 16 + lm;
            out[((size_t)b * H_ + e0 + 0) * T_ + t] = acc[mf][nf][0] + bv.x;
            out[((size_t)b * H_ + e0 + 1) * T_ + t] = acc[mf][nf][1] + bv.y;
            out[((size_t)b * H_ + e0 + 2) * T_ + t] = acc[mf][nf][2] + bv.z;
            out[((size_t)b * H_ + e0 + 3) * T_ + t] = acc[mf][nf][3] + bv.w;
        }
    }
}

// =====================================================================
extern "C" void kernel_launch(void* const* d_in, const int* in_sizes, int n_in,
                              void* d_out, int out_size, void* d_ws, size_t ws_size,
                              hipStream_t stream) {
    const float* x     = (const float*)d_in[0];
    const float* Wfc   = (const float*)d_in[1];
    const float* bfc   = (const float*)d_in[2];
    const float* Wih_f = (const float*)d_in[3];
    const float* Whh_f = (const float*)d_in[4];
    const float* b_f   = (const float*)d_in[5];
    const float* Wih_b = (const float*)d_in[6];
    const float* Whh_b = (const float*)d_in[7];
    const float* b_b   = (const float*)d_in[8];
    const float* Wout  = (const float*)d_in[9];
    const float* bout  = (const float*)d_in[10];
    float* out = (float*)d_out;

    char* ws = (char*)d_ws;
    uint16_t* Xp    = (uint16_t*)(ws);                 // 33,554,432 B
    uint16_t* hsB   = (uint16_t*)(ws + 33554432);      //  8,388,608 B
    uint16_t* WfcB  = (uint16_t*)(ws + 41943040);      //    524,288 B
    uint16_t* WihB  = (uint16_t*)(ws + 42467328);      //    262,144 B
    uint16_t* WhhB  = (uint16_t*)(ws + 42729472);      //    262,144 B
    uint16_t* WoutB = (uint16_t*)(ws + 42991616);      //     65,536 B

    k_cvt_all<<<dim3(544), 256, 0, stream>>>(Wfc, Wih_f, Wih_b, Whh_f, Whh_b, Wout,
                                             WfcB, WihB, WhhB, WoutB);
    k_fc1x <<<dim3(16, 32),  256, 0, stream>>>(x, WfcB, bfc, WihB, b_f, b_b, Xp);
    k_lstm <<<dim3(32, 2),   512, 0, stream>>>(Xp, WhhB, hsB);
    k_outm <<<dim3(8, 2, 32), 256, 0, stream>>>(WoutB, hsB, bout, out);
}

// Round 3
// 280.111 us; speedup vs baseline: 1.0933x; 1.0933x over previous
//
#include <hip/hip_runtime.h>
#include <stdint.h>

typedef __attribute__((ext_vector_type(8))) short short8;
typedef __attribute__((ext_vector_type(4))) float floatx4;

// ---------- helpers ----------
__device__ __forceinline__ float bf16_to_f(uint16_t u) {
    union { uint32_t i; float f; } v; v.i = ((uint32_t)u) << 16; return v.f;
}
__device__ __forceinline__ uint16_t f_to_bf16(float f) {
    union { uint32_t i; float f; } v; v.f = f;
    uint32_t u = v.i;
    u += 0x7FFFu + ((u >> 16) & 1u);   // round-to-nearest-even
    return (uint16_t)(u >> 16);
}
__device__ __forceinline__ void gload16(const void* g, void* l) {
    __builtin_amdgcn_global_load_lds(
        (const __attribute__((address_space(1))) void*)g,
        (__attribute__((address_space(3))) void*)l, 16, 0, 0);
}
__device__ __forceinline__ float rcpf(float x) { return __builtin_amdgcn_rcpf(x); }

// LDS-only barrier: waits own LDS ops, does NOT drain vmcnt (global loads /
// stores stay in flight across it).
__device__ __forceinline__ void bar_lds() {
    asm volatile("s_waitcnt lgkmcnt(0)" ::: "memory");
    __builtin_amdgcn_s_barrier();
    asm volatile("" ::: "memory");
}

#define B_  32
#define T_  512
#define CF_ 2048
#define H_  128
#define G4_ 512   // 4*H
#define LOG2E 1.4426950408889634f

// =====================================================================
// k_cvt_all: all 6 weight tensors fp32 -> bf16 in ONE launch.
// =====================================================================
__global__ __launch_bounds__(256) void k_cvt_all(
        const float* __restrict__ Wfc, const float* __restrict__ Wih_f,
        const float* __restrict__ Wih_b, const float* __restrict__ Whh_f,
        const float* __restrict__ Whh_b, const float* __restrict__ Wout,
        uint16_t* __restrict__ WfcB, uint16_t* __restrict__ WihB,
        uint16_t* __restrict__ WhhB, uint16_t* __restrict__ WoutB) {
    const int blk = blockIdx.x;
    const float* s; uint16_t* d; int off;
    if (blk < 256)      { s = Wfc;   d = WfcB;          off = blk; }
    else if (blk < 320) { s = Wih_f; d = WihB;          off = blk - 256; }
    else if (blk < 384) { s = Wih_b; d = WihB + 65536;  off = blk - 320; }
    else if (blk < 448) { s = Whh_f; d = WhhB;          off = blk - 384; }
    else if (blk < 512) { s = Whh_b; d = WhhB + 65536;  off = blk - 448; }
    else                { s = Wout;  d = WoutB;         off = blk - 512; }
    const int i = off * 1024 + threadIdx.x * 4;
    float4 v = *(const float4*)&s[i];
    ushort4 o;
    o.x = f_to_bf16(v.x); o.y = f_to_bf16(v.y);
    o.z = f_to_bf16(v.z); o.w = f_to_bf16(v.w);
    *(ushort4*)&d[i] = o;
}

// =====================================================================
// k_fc1x: fused  x-transpose + fc1 + input-projection.
// (round-0 best version, 512 thr, plain __syncthreads — control kernel)
// =====================================================================
__global__ __launch_bounds__(512) void k_fc1x(const float* __restrict__ x,
                                              const uint16_t* __restrict__ WfcB,
                                              const float* __restrict__ bfc,
                                              const uint16_t* __restrict__ WihB,
                                              const float* __restrict__ b_f,
                                              const float* __restrict__ b_b,
                                              uint16_t* __restrict__ Xp) {
    __shared__ float tile[64 * 65];                    // [t][cf] fp32
    __shared__ __align__(16) uint16_t As[8192];        // W chunk-major
    __shared__ __align__(16) uint16_t Bs[4224];        // xT chunk-major (stride 66)
    __shared__ __align__(16) uint16_t Hs2[8432];       // Hfc chunk-major (stride 66)

    const int bb = blockIdx.y, n0 = blockIdx.x * 64;
    const int tid = threadIdx.x, w = tid >> 6, l = tid & 63;
    const int lm = l & 15, lk = l >> 4;
    const float* xb = x + (size_t)bb * CF_ * T_;

    // stage-1 mapping (x load / tile write)
    const int t4 = (tid & 15) * 4, cf_r = tid >> 4;    // cf_r in 0..31 (+32)
    // stage-2 mapping (tile read / Bs write)
    const int kk = (tid & 15) * 4, t_r = tid >> 4;     // t_r in 0..31 (+32)

    float4 xv0, xv1;
    {
        const float* p = &xb[(size_t)(0 + cf_r) * T_ + n0 + t4];
        xv0 = *(const float4*)p;
        xv1 = *(const float4*)(p + 32 * T_);
    }

    // ---------------- Phase A ----------------
    const int wmA = (w >> 1) * 32, wnA = (w & 1) * 32;
    floatx4 acc[2][2] = {};
    for (int k0 = 0; k0 < CF_; k0 += 64) {
        __syncthreads();
        // stage1: fp32 transpose tile
        tile[(t4 + 0) * 65 + cf_r] = xv0.x;
        tile[(t4 + 1) * 65 + cf_r] = xv0.y;
        tile[(t4 + 2) * 65 + cf_r] = xv0.z;
        tile[(t4 + 3) * 65 + cf_r] = xv0.w;
        tile[(t4 + 0) * 65 + cf_r + 32] = xv1.x;
        tile[(t4 + 1) * 65 + cf_r + 32] = xv1.y;
        tile[(t4 + 2) * 65 + cf_r + 32] = xv1.z;
        tile[(t4 + 3) * 65 + cf_r + 32] = xv1.w;
        // A staging: wave w stages chunk w (k-offset w*8), rows l and 64+l
        gload16(WfcB + (size_t)l * CF_ + k0 + w * 8,        As + (w * 128 + l) * 8);
        gload16(WfcB + (size_t)(64 + l) * CF_ + k0 + w * 8, As + (w * 128 + 64 + l) * 8);
        __syncthreads();
        // prefetch next x block
        if (k0 + 64 < CF_) {
            const float* p = &xb[(size_t)(k0 + 64 + cf_r) * T_ + n0 + t4];
            xv0 = *(const float4*)p;
            xv1 = *(const float4*)(p + 32 * T_);
        }
        // stage2: tile -> bf16 chunk-major Bs
        #pragma unroll
        for (int pass = 0; pass < 2; ++pass) {
            const int tr = t_r + pass * 32;
            ushort4 o;
            o.x = f_to_bf16(tile[tr * 65 + kk + 0]);
            o.y = f_to_bf16(tile[tr * 65 + kk + 1]);
            o.z = f_to_bf16(tile[tr * 65 + kk + 2]);
            o.w = f_to_bf16(tile[tr * 65 + kk + 3]);
            *(ushort4*)&Bs[((kk >> 3) * 66 + tr) * 8 + (kk & 7)] = o;
        }
        __syncthreads();
        // frags + MFMA
        short8 a[2][2], bfr[2][2];
        #pragma unroll
        for (int kf = 0; kf < 2; ++kf) {
            #pragma unroll
            for (int mf = 0; mf < 2; ++mf)
                a[mf][kf] = *(const short8*)&As[((kf * 4 + lk) * 128 + wmA + mf * 16 + lm) * 8];
            #pragma unroll
            for (int nf = 0; nf < 2; ++nf)
                bfr[nf][kf] = *(const short8*)&Bs[((kf * 4 + lk) * 66 + wnA + nf * 16 + lm) * 8];
        }
        #pragma unroll
        for (int mf = 0; mf < 2; ++mf)
            #pragma unroll
            for (int nf = 0; nf < 2; ++nf) {
                acc[mf][nf] = __builtin_amdgcn_mfma_f32_16x16x32_bf16(a[mf][0], bfr[nf][0], acc[mf][nf], 0, 0, 0);
                acc[mf][nf] = __builtin_amdgcn_mfma_f32_16x16x32_bf16(a[mf][1], bfr[nf][1], acc[mf][nf], 0, 0, 0);
            }
    }
    __syncthreads();
    // epilogue A: bias + bf16 -> Hs2 chunk-major (stride 66)
    #pragma unroll
    for (int mf = 0; mf < 2; ++mf) {
        const int d0 = wmA + mf * 16 + lk * 4;
        const float4 bv = *(const float4*)&bfc[d0];
        const int c = ((wmA + mf * 16) >> 3) + (lk >> 1);
        #pragma unroll
        for (int nf = 0; nf < 2; ++nf) {
            const int t = wnA + nf * 16 + lm;
            ushort4 o;
            o.x = f_to_bf16(acc[mf][nf][0] + bv.x);
            o.y = f_to_bf16(acc[mf][nf][1] + bv.y);
            o.z = f_to_bf16(acc[mf][nf][2] + bv.z);
            o.w = f_to_bf16(acc[mf][nf][3] + bv.w);
            *(ushort4*)&Hs2[(c * 66 + t) * 8 + (lk & 1) * 4] = o;
        }
    }
    __syncthreads();

    // ---------------- Phase B ----------------
    const int dirw = w >> 2;
    const int db   = dirw * B_ + bb;
    const uint16_t* Wp = WihB + (size_t)dirw * (G4_ * H_);
    const float* bi = dirw ? b_b : b_f;
    #pragma unroll
    for (int it = 0; it < 2; ++it) {
        const int gbase = (w & 3) * 64 + it * 256;
        short8 aw[4][4];
        #pragma unroll
        for (int mf = 0; mf < 4; ++mf)
            #pragma unroll
            for (int kf = 0; kf < 4; ++kf)
                aw[mf][kf] = *(const short8*)&Wp[(size_t)(gbase + mf * 16 + lm) * H_ + kf * 32 + lk * 8];
        floatx4 acc2[4][4] = {};
        #pragma unroll
        for (int nf = 0; nf < 4; ++nf) {
            short8 bbf[4];
            #pragma unroll
            for (int kf = 0; kf < 4; ++kf)
                bbf[kf] = *(const short8*)&Hs2[((kf * 4 + lk) * 66 + nf * 16 + lm) * 8];
            #pragma unroll
            for (int mf = 0; mf < 4; ++mf)
                #pragma unroll
                for (int kf = 0; kf < 4; ++kf)
                    acc2[mf][nf] = __builtin_amdgcn_mfma_f32_16x16x32_bf16(aw[mf][kf], bbf[kf], acc2[mf][nf], 0, 0, 0);
        }
        #pragma unroll
        for (int mf = 0; mf < 4; ++mf) {
            const int g0 = gbase + mf * 16 + lk * 4;
            const float4 bv = *(const float4*)&bi[g0];
            #pragma unroll
            for (int nf = 0; nf < 4; ++nf) {
                const int t = n0 + nf * 16 + lm;
                ushort4 o;
                o.x = f_to_bf16(acc2[mf][nf][0] + bv.x);
                o.y = f_to_bf16(acc2[mf][nf][1] + bv.y);
                o.z = f_to_bf16(acc2[mf][nf][2] + bv.z);
                o.w = f_to_bf16(acc2[mf][nf][3] + bv.w);
                *(ushort4*)&Xp[((size_t)db * T_ + t) * G4_ + g0] = o;
            }
        }
    }
}

// =====================================================================
// k_lstm REWRITE: gate-sliced wave layout.
// Wave w computes n-frags at g = q*128 + w*16 (q = gate index 0..3), so
// each lane's accumulators hold ALL FOUR gates for its (t = 4*lk+r,
// hh = 16*w+lm). Activation is fully in-register: z_sh eliminated
// (-32 LDS ops/thread/step), ONE barrier per step (double-buffered h_sh),
// and Xp gate-inputs for step s+1 prefetched during step s's MFMA phase.
// Numerics identical to previous version.
// =====================================================================
__global__ __launch_bounds__(512) void k_lstm(const uint16_t* __restrict__ Xp,
                                              const uint16_t* __restrict__ WhhB,
                                              uint16_t* __restrict__ hs) {
    __shared__ __align__(16) uint16_t h_sh[2][16 * 136];
    const int dir = blockIdx.y, t0 = blockIdx.x * 16;
    const int tid = threadIdx.x, w = tid >> 6, l = tid & 63;
    const int lm = l & 15, lk = l >> 4;
    const int gcol = w * 16 + lm;          // h-column this lane owns
    const int tloc = lk * 4;               // t-row base this lane owns
    const uint16_t* Wp = WhhB + dir * (G4_ * H_);

    // B-frags: bw[q][kf] = Whh rows g = q*128 + gcol, k-chunk kf
    short8 bw[4][4];
    #pragma unroll
    for (int q = 0; q < 4; ++q)
        #pragma unroll
        for (int kf = 0; kf < 4; ++kf)
            bw[q][kf] = *(const short8*)&Wp[(size_t)(q * H_ + gcol) * H_ + kf * 32 + lk * 8];

    for (int i = tid; i < 16 * 136; i += 512) h_sh[0][i] = 0;
    float c[4] = {0.f, 0.f, 0.f, 0.f};

    uint16_t xva[4][4], xvb[4][4];
    // preload step 0 gate-inputs
    {
        const int b0 = dir ? (B_ - 1) : 0;
        const uint16_t* xp = Xp + ((size_t)(dir * B_ + b0) * T_ + t0 + tloc) * G4_;
        #pragma unroll
        for (int r = 0; r < 4; ++r)
            #pragma unroll
            for (int q = 0; q < 4; ++q)
                xva[r][q] = xp[(size_t)r * G4_ + q * H_ + gcol];
    }
    bar_lds();   // h_sh[0] zeros visible

    auto step = [&](int s, uint16_t (&xc)[4][4], uint16_t (&xn)[4][4], int par) {
        const int b_idx = dir ? (B_ - 1 - s) : s;
        // A-frags from h(prev)
        short8 af[4];
        #pragma unroll
        for (int kf = 0; kf < 4; ++kf)
            af[kf] = *(const short8*)&h_sh[par][lm * 136 + kf * 32 + lk * 8];
        floatx4 acc[4] = {};
        #pragma unroll
        for (int q = 0; q < 4; ++q)
            #pragma unroll
            for (int kf = 0; kf < 4; ++kf)
                acc[q] = __builtin_amdgcn_mfma_f32_16x16x32_bf16(af[kf], bw[q][kf], acc[q], 0, 0, 0);
        // prefetch next step's gate-inputs (hidden under MFMA + activation)
        if (s < B_ - 1) {
            const int bn = dir ? (B_ - 2 - s) : (s + 1);
            const uint16_t* xp = Xp + ((size_t)(dir * B_ + bn) * T_ + t0 + tloc) * G4_;
            #pragma unroll
            for (int r = 0; r < 4; ++r)
                #pragma unroll
                for (int q = 0; q < 4; ++q)
                    xn[r][q] = xp[(size_t)r * G4_ + q * H_ + gcol];
        }
        // in-register activation; write h to h_sh[par^1] + global hs
        #pragma unroll
        for (int r = 0; r < 4; ++r) {
            float zi = acc[0][r] + bf16_to_f(xc[r][0]);
            float zf = acc[1][r] + bf16_to_f(xc[r][1]);
            float zg = acc[2][r] + bf16_to_f(xc[r][2]);
            float zo = acc[3][r] + bf16_to_f(xc[r][3]);
            float si = rcpf(1.f + __builtin_amdgcn_exp2f(-LOG2E * zi));
            float sf = rcpf(1.f + __builtin_amdgcn_exp2f(-LOG2E * zf));
            float so = rcpf(1.f + __builtin_amdgcn_exp2f(-LOG2E * zo));
            float tg = 1.f - 2.f * rcpf(1.f + __builtin_amdgcn_exp2f(2.f * LOG2E * zg));
            c[r] = sf * c[r] + si * tg;
            float tc = 1.f - 2.f * rcpf(1.f + __builtin_amdgcn_exp2f(2.f * LOG2E * c[r]));
            float hn = so * tc;
            uint16_t hb = f_to_bf16(hn);
            h_sh[par ^ 1][(tloc + r) * 136 + gcol] = hb;
            hs[((size_t)b_idx * T_ + t0 + tloc + r) * 256 + dir * H_ + gcol] = hb;
        }
        bar_lds();   // ONE barrier per step: h(next) visible, prev reads done
    };

    for (int s2 = 0; s2 < 16; ++s2) {
        step(2 * s2,     xva, xvb, 0);
        step(2 * s2 + 1, xvb, xva, 1);
    }
}

// =====================================================================
// k_outm: out[b][e][t] fp32 = W_out(128x256) @ hs[b]^T + b_out
// 64x64 tiles, BK=64, grid (8, 2, 32)
// =====================================================================
__global__ __launch_bounds__(256) void k_outm(const uint16_t* __restrict__ WoutB,
                                              const uint16_t* __restrict__ hs,
                                              const float* __restrict__ bout,
                                              float* __restrict__ out) {
    __shared__ __align__(16) uint16_t As[4096], Bs[4096];
    const int b = blockIdx.z, m0 = blockIdx.y * 64, n0 = blockIdx.x * 64;
    const int tid = threadIdx.x, w = tid >> 6, l = tid & 63;
    const int wm = (w >> 1) * 32, wn = (w & 1) * 32;
    const int lm = l & 15, lk = l >> 4;
    const uint16_t* A = WoutB + (size_t)m0 * 256;
    const uint16_t* Bp = hs + ((size_t)b * T_ + n0) * 256;
    floatx4 acc[2][2] = {};
    const uint16_t* gA = A + (size_t)l * 256;
    const uint16_t* gB = Bp + (size_t)l * 256;
    for (int k0 = 0; k0 < 256; k0 += 64) {
        __syncthreads();
        gload16(gA + k0 + (2 * w) * 8,     As + ((2 * w) * 64 + l) * 8);
        gload16(gA + k0 + (2 * w + 1) * 8, As + ((2 * w + 1) * 64 + l) * 8);
        gload16(gB + k0 + (2 * w) * 8,     Bs + ((2 * w) * 64 + l) * 8);
        gload16(gB + k0 + (2 * w + 1) * 8, Bs + ((2 * w + 1) * 64 + l) * 8);
        __syncthreads();
        short8 a[2][2], bfr[2][2];
        #pragma unroll
        for (int kf = 0; kf < 2; ++kf) {
            #pragma unroll
            for (int mf = 0; mf < 2; ++mf)
                a[mf][kf] = *(const short8*)&As[((kf * 4 + lk) * 64 + wm + mf * 16 + lm) * 8];
            #pragma unroll
            for (int nf = 0; nf < 2; ++nf)
                bfr[nf][kf] = *(const short8*)&Bs[((kf * 4 + lk) * 64 + wn + nf * 16 + lm) * 8];
        }
        #pragma unroll
        for (int mf = 0; mf < 2; ++mf)
            #pragma unroll
            for (int nf = 0; nf < 2; ++nf) {
                acc[mf][nf] = __builtin_amdgcn_mfma_f32_16x16x32_bf16(a[mf][0], bfr[nf][0], acc[mf][nf], 0, 0, 0);
                acc[mf][nf] = __builtin_amdgcn_mfma_f32_16x16x32_bf16(a[mf][1], bfr[nf][1], acc[mf][nf], 0, 0, 0);
            }
    }
    #pragma unroll
    for (int mf = 0; mf < 2; ++mf) {
        const int e0 = m0 + wm + mf * 16 + lk * 4;
        const float4 bv = *(const float4*)&bout[e0];
        #pragma unroll
        for (int nf = 0; nf < 2; ++nf) {
            const int t = n0 + wn + nf * 16 + lm;
            out[((size_t)b * H_ + e0 + 0) * T_ + t] = acc[mf][nf][0] + bv.x;
            out[((size_t)b * H_ + e0 + 1) * T_ + t] = acc[mf][nf][1] + bv.y;
            out[((size_t)b * H_ + e0 + 2) * T_ + t] = acc[mf][nf][2] + bv.z;
            out[((size_t)b * H_ + e0 + 3) * T_ + t] = acc[mf][nf][3] + bv.w;
        }
    }
}

// =====================================================================
extern "C" void kernel_launch(void* const* d_in, const int* in_sizes, int n_in,
                              void* d_out, int out_size, void* d_ws, size_t ws_size,
                              hipStream_t stream) {
    const float* x     = (const float*)d_in[0];
    const float* Wfc   = (const float*)d_in[1];
    const float* bfc   = (const float*)d_in[2];
    const float* Wih_f = (const float*)d_in[3];
    const float* Whh_f = (const float*)d_in[4];
    const float* b_f   = (const float*)d_in[5];
    const float* Wih_b = (const float*)d_in[6];
    const float* Whh_b = (const float*)d_in[7];
    const float* b_b   = (const float*)d_in[8];
    const float* Wout  = (const float*)d_in[9];
    const float* bout  = (const float*)d_in[10];
    float* out = (float*)d_out;

    char* ws = (char*)d_ws;
    uint16_t* Xp    = (uint16_t*)(ws);                 // 33,554,432 B
    uint16_t* hsB   = (uint16_t*)(ws + 33554432);      //  8,388,608 B
    uint16_t* WfcB  = (uint16_t*)(ws + 41943040);      //    524,288 B
    uint16_t* WihB  = (uint16_t*)(ws + 42467328);      //    262,144 B
    uint16_t* WhhB  = (uint16_t*)(ws + 42729472);      //    262,144 B
    uint16_t* WoutB = (uint16_t*)(ws + 42991616);      //     65,536 B

    k_cvt_all<<<dim3(544), 256, 0, stream>>>(Wfc, Wih_f, Wih_b, Whh_f, Whh_b, Wout,
                                             WfcB, WihB, WhhB, WoutB);
    k_fc1x <<<dim3(8, 32),   512, 0, stream>>>(x, WfcB, bfc, WihB, b_f, b_b, Xp);
    k_lstm <<<dim3(32, 2),   512, 0, stream>>>(Xp, WhhB, hsB);
    k_outm <<<dim3(8, 2, 32), 256, 0, stream>>>(WoutB, hsB, bout, out);
}